// Round 4
// baseline (312.161 us; speedup 1.0000x reference)
//
#include <hip/hip_runtime.h>
#include <stdint.h>
#include <stddef.h>

// RadialCTC: cosine logits (norm_scale=32) -> log_softmax -> CTC(sum).
// Strategy: never materialize the (16384 x 1296) logits. GEMM (f16 MFMA)
// computes per-row sum(exp(logit)) fused in the epilogue; label log-probs via
// small f16 MFMA gather-GEMM; CTC alpha recursion one wave per sample.
// R9: linear f64 + pow2 renorm ctc. R11: XOR channel-slot LDS swizzle.
// R12: 9 -> 4 dispatches: NO CHANGE -> per-node gap ~= 0.
// R14: log2(sumexp) factored out of recursion (Msum); gather made independent
// of gemm and fused into same dispatch: only -2us. Model that fits R0/R12/R14:
// dur includes the harness 268MB poison fill (~44.5us) + ~116us pipeline, and
// the three phases are strictly serial with ctc (32 waves) fully exposed.
// R15 (this round): OVERLAP ctc with gemm. Single mega kernel:
//   blocks 0..31   ctc: spin on gather_done==256 (acquire), beta chain runs
//                  CONCURRENTLY with gemm; spin gemm_done==1408; Msum + nll;
//                  last ctc block sums -> out.
//   blocks 32..287 gather jobs (early dispatch), release-count cnt[0].
//   blocks 288..   gemm jobs, release-count cnt[1].
// No grid.sync / cooperative launch needed: only 32 blocks spin, all
// producers have lower IDs + free capacity -> guaranteed forward progress.
// Publish = fence + syncthreads + release-add; consume = acquire loads.

typedef _Float16 f16;
typedef _Float16 f16x8 __attribute__((ext_vector_type(8)));
typedef float f32x4 __attribute__((ext_vector_type(4)));
typedef __attribute__((address_space(1))) void* as1_void_ptr;
typedef __attribute__((address_space(3))) void* as3_void_ptr;

#define TT 512
#define NN 32
#define CC 1296
#define DD 512
#define SS 30
#define CP 1408   // C padded to 11*128 for GEMM tiling (pad rows are zero)
#define LL 61     // 2*S+1 CTC states
#define NORM_SCALE 32.0f
#define LOG2E 1.4426950408889634f
#define LN2   0.6931471805599453f

#define PREP_WBLK (CP / 16)            // 88 c-tiles of 16 (covers pad -> zeros)
#define PREP_ZBLK 17                   // 16 zero sumexp + 1 zero counters
#define PREP_FBLK (TT * NN / 4)        // 4096 fnorm blocks (4 rows each)

#define GEMM_BLK ((TT * NN / 128) * (CP / 128))   // 128*11 = 1408
#define GATH_BLK (NN * (TT / 64))                 // 32*8  = 256
#define MEGA_CTC 32
#define MEGA_GATH0 MEGA_CTC                        // 32
#define MEGA_GEMM0 (MEGA_CTC + GATH_BLK)           // 288
#define MEGA_BLK  (MEGA_GEMM0 + GEMM_BLK)          // 1696

__device__ __forceinline__ float fexp2(float x) { return __builtin_amdgcn_exp2f(x); }
__device__ __forceinline__ float flog2(float x) { return __builtin_amdgcn_logf(x); }

__device__ __forceinline__ void wait_cnt(unsigned* p, unsigned target) {
    while (__hip_atomic_load(p, __ATOMIC_ACQUIRE, __HIP_MEMORY_SCOPE_AGENT) < target)
        __builtin_amdgcn_s_sleep(8);
}
__device__ __forceinline__ void post_cnt(unsigned* p) {
    __hip_atomic_fetch_add(p, 1u, __ATOMIC_RELEASE, __HIP_MEMORY_SCOPE_AGENT);
}

// whole-wave shift-right-by-1 of a double (two 32-bit DPPs, ctrl 0x138 =
// WAVE_SHR1). Lane 0 receives +0.0.
__device__ __forceinline__ double dpp_sr1_zero64(double x) {
    long long b = __double_as_longlong(x);
    int lo = (int)(b & 0xFFFFFFFFLL);
    int hi = (int)(b >> 32);
    int lo2 = __builtin_amdgcn_update_dpp(0, lo, 0x138, 0xF, 0xF, false);
    int hi2 = __builtin_amdgcn_update_dpp(0, hi, 0x138, 0xF, 0xF, false);
    return __longlong_as_double(((long long)hi2 << 32) |
                                (unsigned long long)(unsigned int)lo2);
}
// one level of DPP row-shr int max (identity 0; operands are >=0 hi-words)
template <int CTRL>
__device__ __forceinline__ int dpp_imax_level(int m) {
    int t = __builtin_amdgcn_update_dpp(0, m, CTRL, 0xF, 0xF, false);
    return m > t ? m : t;
}

// ---- fused prep: W column-norm + transpose to f16 (atomic-free, per-block
//      column ownership), feats row-normalize -> f16, and zeroing of
//      sumexp + the 3 flow counters. Sectioned by blockIdx.x. ----
__global__ __launch_bounds__(256) void prep_kernel(const float* __restrict__ W,
                                                   const float* __restrict__ feats,
                                                   f16* __restrict__ wt,
                                                   f16* __restrict__ fn,
                                                   float* __restrict__ sumexp,
                                                   unsigned* __restrict__ cnt) {
    int bx = blockIdx.x, tid = threadIdx.x;
    if (bx < PREP_WBLK) {
        // ---- W-prep: this block owns 16 columns c0..c0+15 ----
        __shared__ float red[256];
        __shared__ float rqs[16];
        int c0 = bx * 16;
        int cl = tid & 15, dg = tid >> 4;
        int c = c0 + cl;
        float ss = 0.f;
        if (c < CC) {
            for (int d = dg; d < DD; d += 16) {
                float v = W[(size_t)d * CC + c];
                ss += v * v;
            }
        }
        red[tid] = ss;
        __syncthreads();
        if (tid < 16) {
            float s2 = 0.f;
            #pragma unroll
            for (int k = 0; k < 16; ++k) s2 += red[tid + 16 * k];
            rqs[tid] = rsqrtf(s2);
        }
        __syncthreads();
        // write wt[c][d] (f16), 16 consecutive-d lanes per c; W re-reads hit L1
        int c_loc = tid >> 4, dl = tid & 15;
        int cc = c0 + c_loc;
        float rq = rqs[c_loc];
        #pragma unroll 4
        for (int it = 0; it < 32; ++it) {
            int d = dl + it * 16;
            float v = (cc < CC) ? W[(size_t)d * CC + cc] * rq : 0.f;
            wt[(size_t)cc * DD + d] = (f16)v;
        }
    } else if (bx < PREP_WBLK + PREP_ZBLK) {
        int zb = bx - PREP_WBLK;
        if (zb < 16) {
            float4 z = {0.f, 0.f, 0.f, 0.f};
            ((float4*)sumexp)[zb * 256 + tid] = z;   // 16*256*16B = 64KB
        } else if (tid < 3) {
            cnt[tid] = 0u;
        }
    } else {
        // ---- fnorm: one wave per feats row ----
        int fb = bx - PREP_WBLK - PREP_ZBLK;
        int wv = (fb * 256 + tid) >> 6;  // row id, 0..16383
        int lane = tid & 63;
        const float4* src = (const float4*)(feats + (size_t)wv * DD) + lane * 2;
        float4 a = src[0], b = src[1];
        float ss = a.x*a.x + a.y*a.y + a.z*a.z + a.w*a.w
                 + b.x*b.x + b.y*b.y + b.z*b.z + b.w*b.w;
        #pragma unroll
        for (int off = 32; off; off >>= 1) ss += __shfl_xor(ss, off);
        float r = rsqrtf(ss);
        f16x8 o;
        o[0]=(f16)(a.x*r); o[1]=(f16)(a.y*r); o[2]=(f16)(a.z*r); o[3]=(f16)(a.w*r);
        o[4]=(f16)(b.x*r); o[5]=(f16)(b.y*r); o[6]=(f16)(b.z*r); o[7]=(f16)(b.w*r);
        *(f16x8*)(fn + (size_t)wv * DD + lane * 8) = o;
    }
}

// ---- mega kernel: ctc (blocks 0..31) + gather (32..287) + gemm (288..1695).
//      cnt[0]=gather_done, cnt[1]=gemm_done, cnt[2]=nll_done.
//      LDS channel-slot XOR swizzle: (row,ch) stored at slot ch^((row>>1)&3). ----
__global__ __launch_bounds__(256) void mega_kernel(const f16* __restrict__ A,
                                                   const f16* __restrict__ B,
                                                   const int* __restrict__ labels,
                                                   const int* __restrict__ in_lens,
                                                   const int* __restrict__ lab_lens,
                                                   float* __restrict__ sumexp,
                                                   float* __restrict__ lp_lab,
                                                   float* __restrict__ nll,
                                                   unsigned* __restrict__ cnt,
                                                   float* __restrict__ out) {
    __shared__ __align__(16) f16 sm[8192];   // 16 KB (gemm: all; gather: 3/8)
    int bx = blockIdx.x;
    int tid = threadIdx.x;
    int w = tid >> 6, lane = tid & 63;
    int lm = lane & 15, hi = lane >> 4;
    int sw = (lm >> 1) & 3;                // fragment-read channel swizzle

    if (bx >= MEGA_GEMM0) {
        // ================= GEMM section =================
        int j = bx - MEGA_GEMM0;
        int bm = j & 127, bn = j >> 7;         // 1408 = 128 * 11
        int wm = w >> 1, wn = w & 1;           // 2x2 wave grid -> 64x64 per wave
        f32x4 acc[4][4];
        f32x4 zero = {0.f, 0.f, 0.f, 0.f};
        #pragma unroll
        for (int i = 0; i < 4; ++i)
            #pragma unroll
            for (int jj = 0; jj < 4; ++jj) acc[i][jj] = zero;

        for (int kb = 0; kb < 16; ++kb) {      // K=512, BK=32 (one MFMA K-step)
            #pragma unroll
            for (int p = 0; p < 2; ++p) {
                int s = p * 256 + tid;         // segment id, 16B each; 512 segs/tile
                int row = s >> 2;
                int ch = (s & 3) ^ ((row >> 1) & 3);   // swizzled source channel
                const f16* ga = A + (size_t)(bm * 128 + row) * DD + kb * 32 + ch * 8;
                const f16* gb = B + (size_t)(bn * 128 + row) * DD + kb * 32 + ch * 8;
                // LDS dest = wave-uniform base + lane*16 (contiguous, required)
                __builtin_amdgcn_global_load_lds((as1_void_ptr)ga,
                    (as3_void_ptr)&sm[(p * 256 + w * 64) * 8], 16, 0, 0);
                __builtin_amdgcn_global_load_lds((as1_void_ptr)gb,
                    (as3_void_ptr)&sm[4096 + (p * 256 + w * 64) * 8], 16, 0, 0);
            }
            __syncthreads();
            f16x8 af[4], bf[4];
            #pragma unroll
            for (int i = 0; i < 4; ++i)
                af[i] = *(const f16x8*)&sm[(wm * 64 + i * 16 + lm) * 32 + (hi ^ sw) * 8];
            #pragma unroll
            for (int jj = 0; jj < 4; ++jj)
                bf[jj] = *(const f16x8*)&sm[4096 + (wn * 64 + jj * 16 + lm) * 32 + (hi ^ sw) * 8];
            #pragma unroll
            for (int i = 0; i < 4; ++i)
                #pragma unroll
                for (int jj = 0; jj < 4; ++jj)
                    acc[i][jj] = __builtin_amdgcn_mfma_f32_16x16x32_f16(af[i], bf[jj], acc[i][jj], 0, 0, 0);
            __syncthreads();
        }
        // epilogue: per-row sum of exp(32*logit) over this block's 128 columns
        #pragma unroll
        for (int i = 0; i < 4; ++i) {
            float rs[4] = {0.f, 0.f, 0.f, 0.f};
            #pragma unroll
            for (int jj = 0; jj < 4; ++jj) {
                int c = bn * 128 + wn * 64 + jj * 16 + lm;   // C/D: col = lane&15
                bool ok = (c < CC);
                #pragma unroll
                for (int r = 0; r < 4; ++r)
                    rs[r] += ok ? fexp2(acc[i][jj][r] * (NORM_SCALE * LOG2E)) : 0.f;
            }
            #pragma unroll
            for (int off = 1; off < 16; off <<= 1) {        // sum over 16 cols
                #pragma unroll
                for (int r = 0; r < 4; ++r) rs[r] += __shfl_xor(rs[r], off);
            }
            if (lm == 0) {
                int rowb = bm * 128 + wm * 64 + i * 16 + hi * 4;  // row = quad*4+reg
                #pragma unroll
                for (int r = 0; r < 4; ++r) atomicAdd(&sumexp[rowb + r], rs[r]);
            }
        }
        __threadfence();
        __syncthreads();
        if (tid == 0) post_cnt(&cnt[1]);
    } else if (bx >= MEGA_GATH0) {
        // ================= gather section: 6 KB LDS, K-looped stage =========
        int gbx = bx - MEGA_GATH0;
        int n = gbx & 31, t0 = (gbx >> 5) * 64;
        // per-thread staging sources (constant across kb)
        int arow = tid >> 2;                       // 0..63 (A: 256 segs of 16B)
        int ach = (tid & 3) ^ ((arow >> 1) & 3);
        const f16* gaB = A + (size_t)((t0 + arow) * NN + n) * DD + ach * 8;
        int brow = tid >> 2;                       // valid for tid<128: 0..31
        int bch = (tid & 3) ^ ((brow >> 1) & 3);
        int cls = (brow == 0 || brow > SS) ? 0 : labels[n * SS + brow - 1];
        const f16* gbB = B + (size_t)cls * DD + bch * 8;

        f32x4 acc0 = {0.f, 0.f, 0.f, 0.f};
        f32x4 acc1 = {0.f, 0.f, 0.f, 0.f};
        for (int kb = 0; kb < 16; ++kb) {
            __builtin_amdgcn_global_load_lds((as1_void_ptr)(gaB + kb * 32),
                (as3_void_ptr)&sm[tid * 8], 16, 0, 0);
            if (tid < 128)
                __builtin_amdgcn_global_load_lds((as1_void_ptr)(gbB + kb * 32),
                    (as3_void_ptr)&sm[2048 + tid * 8], 16, 0, 0);
            __syncthreads();
            f16x8 af  = *(const f16x8*)&sm[(w * 16 + lm) * 32 + (hi ^ sw) * 8];
            f16x8 bf0 = *(const f16x8*)&sm[2048 + lm * 32 + (hi ^ sw) * 8];
            f16x8 bf1 = *(const f16x8*)&sm[2048 + (16 + lm) * 32 + (hi ^ sw) * 8];
            acc0 = __builtin_amdgcn_mfma_f32_16x16x32_f16(af, bf0, acc0, 0, 0, 0);
            acc1 = __builtin_amdgcn_mfma_f32_16x16x32_f16(af, bf1, acc1, 0, 0, 0);
            __syncthreads();
        }
        #pragma unroll
        for (int jn = 0; jn < 2; ++jn) {
            int jc = jn * 16 + lm;
            if (jc >= 31) continue;
            float* dst = lp_lab + ((size_t)n * 31 + jc) * TT + t0;
            f32x4 av = jn ? acc1 : acc0;
            #pragma unroll
            for (int r = 0; r < 4; ++r) {
                int tl = w * 16 + hi * 4 + r;
                dst[tl] = av[r] * (NORM_SCALE * LOG2E);   // RAW (no ls2)
            }
        }
        __threadfence();
        __syncthreads();
        if (tid == 0) post_cnt(&cnt[0]);
    } else if (tid < 64) {
        // ================= CTC section (wave 0 of blocks 0..31) =============
        int n = bx;
        int s = tid;             // 64 lanes; states 0..60 valid
        wait_cnt(&cnt[0], GATH_BLK);   // all lp_lab published (acquire)

        bool valid = s < LL;
        int ext = (valid && (s & 1)) ? labels[n * SS + (s >> 1)] : 0;
        int jmap = (valid && (s & 1)) ? ((s >> 1) + 1) : 0;   // state -> class slot
        int ext2 = __shfl_up(ext, 2);
        double skipd = ((s >= 2) && valid && (ext != ext2)) ? 1.0 : 0.0;
        int Tin = in_lens[n];    // wave-uniform; freeze == stop at t = Tin-1
        const float4* g0 = (const float4*)(lp_lab + ((size_t)n * 31 + jmap) * TT);

        float4 cur = g0[0];
        float4 nxt = g0[1];
        float4 nx2 = g0[2];
        double beta = (s <= 1) ? (double)fexp2(cur.x) : 0.0;
        int Mi = 0;              // running log2 scale: alpha_raw = log2(beta) + Mi

        auto stepL = [&](float lp) {
            double P = (double)fexp2(lp);      // |lp| <= ~46.2: f32-safe
            double b1 = dpp_sr1_zero64(beta);
            double b2 = dpp_sr1_zero64(b1);
            beta = (beta + b1 + b2 * skipd) * P;
        };
        auto renorm = [&]() {
            int h = (int)(__double_as_longlong(beta) >> 32);  // beta>=0: monotone
            h = dpp_imax_level<0x111>(h);        // row_shr:1
            h = dpp_imax_level<0x112>(h);        // row_shr:2
            h = dpp_imax_level<0x114>(h);        // row_shr:4
            h = dpp_imax_level<0x118>(h);        // row_shr:8 -> row max 15/31/47/63
            int r0 = __builtin_amdgcn_readlane(h, 15);
            int r1 = __builtin_amdgcn_readlane(h, 31);
            int r2 = __builtin_amdgcn_readlane(h, 47);
            int r3 = __builtin_amdgcn_readlane(h, 63);
            int mx = max(max(r0, r1), max(r2, r3));
            int e11 = mx >> 20;                  // biased 11-bit exponent
            double scale = __longlong_as_double((long long)(2046 - e11) << 52);
            beta *= scale;
            Mi += e11 - 1023;
        };

        // group 0: t = 1..3 (Tin >= 481, always full)
        stepL(cur.y); stepL(cur.z); stepL(cur.w);
        renorm();
        int remaining = Tin - 4;   // steps left (total steps = Tin-1)
        int g = 1;
        while (remaining >= 4) {
            cur = nxt; nxt = nx2;
            int gi = g + 2; if (gi > 127) gi = 127;
            nx2 = g0[gi];
            stepL(cur.x); stepL(cur.y); stepL(cur.z); stepL(cur.w);
            renorm();
            remaining -= 4; ++g;
        }
        cur = nxt;                 // tail 0..3 steps
        if (remaining > 0) stepL(cur.x);
        if (remaining > 1) stepL(cur.y);
        if (remaining > 2) stepL(cur.z);

        wait_cnt(&cnt[1], GEMM_BLK);   // sumexp complete (acquire)

        // Msum = sum_{t<Tin} log2(sumexp[t,n]) -- f64 partials, off beta chain
        double ms = 0.0;
        for (int t = s; t < Tin; t += 64)
            ms += (double)flog2(sumexp[(size_t)t * NN + n]);
        #pragma unroll
        for (int off = 32; off; off >>= 1) ms += __shfl_xor(ms, off);

        int Ln = 2 * lab_lens[n] + 1;
        double last  = __shfl(beta, Ln - 1);
        double last2 = __shfl(beta, Ln - 2);
        double smv = last + last2;
        long long bb = __double_as_longlong(smv);
        int e = (int)(bb >> 52) - 1023;
        double mant = __longlong_as_double((bb & 0xFFFFFFFFFFFFFLL) | (1023LL << 52));
        float v = (float)(-((double)flog2((float)mant) + (double)(e + Mi) - ms) * LN2);
        if (s == 0) {
            nll[n] = v;
            __threadfence();
            post_cnt(&cnt[2]);
            if (n == 0) {                      // block 0: final deterministic sum
                wait_cnt(&cnt[2], NN);
                float t = 0.f;
                for (int i = 0; i < NN; ++i) t += nll[i];
                out[0] = t;
            }
        }
    }
}

extern "C" void kernel_launch(void* const* d_in, const int* in_sizes, int n_in,
                              void* d_out, int out_size, void* d_ws, size_t ws_size,
                              hipStream_t stream) {
    const float* feats        = (const float*)d_in[0];
    const float* W            = (const float*)d_in[1];
    const int*   labeling     = (const int*)d_in[2];
    const int*   logit_lgts   = (const int*)d_in[3];
    const int*   labeling_lgts= (const int*)d_in[4];
    float* out = (float*)d_out;
    char* ws = (char*)d_ws;

    size_t off = 0;
    f16*   wt     = (f16*)(ws + off);   off += (size_t)CP * DD * 2;        // 1.44 MB
    f16*   fn     = (f16*)(ws + off);   off += (size_t)TT * NN * DD * 2;   // 16.8 MB
    float* sumexp = (float*)(ws + off); off += (size_t)TT * NN * 4;        // 64 KB
    float* lp_lab = (float*)(ws + off); off += (size_t)NN * 31 * TT * 4;   // 2.0 MB
    float* nllb   = (float*)(ws + off); off += 64 * 4;
    unsigned* cnt = (unsigned*)(ws + off); off += 64;

    prep_kernel<<<PREP_WBLK + PREP_ZBLK + PREP_FBLK, 256, 0, stream>>>(
        W, feats, wt, fn, sumexp, cnt);
    mega_kernel<<<MEGA_BLK, 256, 0, stream>>>(fn, wt, labeling, logit_lgts,
                                              labeling_lgts, sumexp, lp_lab,
                                              nllb, cnt, out);

    (void)in_sizes; (void)n_in; (void)out_size; (void)ws_size;
}

// Round 5
// 158.975 us; speedup vs baseline: 1.9636x; 1.9636x over previous
//
#include <hip/hip_runtime.h>
#include <stdint.h>
#include <stddef.h>

// RadialCTC: cosine logits (norm_scale=32) -> log_softmax -> CTC(sum).
// Strategy: never materialize the (16384 x 1296) logits. GEMM (f16 MFMA)
// computes per-row sum(exp(logit)) fused in the epilogue; label log-probs via
// small f16 MFMA gather-GEMM; CTC alpha recursion one wave per sample.
// R9: linear f64 + pow2 renorm ctc. R11: XOR channel-slot LDS swizzle.
// R12: 9 -> 4 dispatches: NO CHANGE -> per-node gap ~= 0.
// R14: log2(sumexp) factored out of recursion (Msum); gather independent of
// gemm, fused as tail blocks: only -2us (160.7).
// R15 FAILED (312us): spin-wait overlap. MfmaUtil 4.07% x 229us = 9.3us MFMA
// busy = the workload's MFMA floor -> compute unchanged, kernel stalled 5x.
// Cause: agent-scope acquire spin loops lower to buffer_inv (L1/L2 inv) and
// per-block releases to buffer_wbl2 -> continuous L2 invalidation on all 8
// XCDs destroyed gemm A/B L2 reuse. LESSON: no device-scope acquire/release
// in hot loops on CDNA4.
// R16 (this round): same overlap, ZERO runtime sync. Each of 32 blocks
// computes its OWN sample's full gather (512 t, K-looped 18KB LDS) then runs
// that sample's beta chain in the SAME block (only __syncthreads needed).
// These 32 long blocks (~3us gather + ~30us ctc) overlap the 1408 gemm
// blocks (~40-45us) in one dispatch; 1440 blocks all co-resident. The
// gemm-dependent Msum moves to a tiny final kernel (ctc stores f64 partial).
// Arithmetic bit-identical to R14 (same MFMA order, same sequential sum).

typedef _Float16 f16;
typedef _Float16 f16x8 __attribute__((ext_vector_type(8)));
typedef float f32x4 __attribute__((ext_vector_type(4)));
typedef __attribute__((address_space(1))) void* as1_void_ptr;
typedef __attribute__((address_space(3))) void* as3_void_ptr;

#define TT 512
#define NN 32
#define CC 1296
#define DD 512
#define SS 30
#define CP 1408   // C padded to 11*128 for GEMM tiling (pad rows are zero)
#define LL 61     // 2*S+1 CTC states
#define NORM_SCALE 32.0f
#define LOG2E 1.4426950408889634f
#define LN2   0.6931471805599453f

#define PREP_WBLK (CP / 16)            // 88 c-tiles of 16 (covers pad -> zeros)
#define PREP_ZBLK 16                   // 16 blocks zero sumexp
#define PREP_FBLK (TT * NN / 4)        // 4096 fnorm blocks (4 rows each)

#define GEMM_BLK ((TT * NN / 128) * (CP / 128))   // 128*11 = 1408
#define MEGA_GC  NN                                // 32 gather+ctc blocks
#define MEGA_BLK (MEGA_GC + GEMM_BLK)              // 1440

__device__ __forceinline__ float fexp2(float x) { return __builtin_amdgcn_exp2f(x); }
__device__ __forceinline__ float flog2(float x) { return __builtin_amdgcn_logf(x); }

// whole-wave shift-right-by-1 of a double (two 32-bit DPPs, ctrl 0x138 =
// WAVE_SHR1). Lane 0 receives +0.0.
__device__ __forceinline__ double dpp_sr1_zero64(double x) {
    long long b = __double_as_longlong(x);
    int lo = (int)(b & 0xFFFFFFFFLL);
    int hi = (int)(b >> 32);
    int lo2 = __builtin_amdgcn_update_dpp(0, lo, 0x138, 0xF, 0xF, false);
    int hi2 = __builtin_amdgcn_update_dpp(0, hi, 0x138, 0xF, 0xF, false);
    return __longlong_as_double(((long long)hi2 << 32) |
                                (unsigned long long)(unsigned int)lo2);
}
// one level of DPP row-shr int max (identity 0; operands are >=0 hi-words)
template <int CTRL>
__device__ __forceinline__ int dpp_imax_level(int m) {
    int t = __builtin_amdgcn_update_dpp(0, m, CTRL, 0xF, 0xF, false);
    return m > t ? m : t;
}

// ---- fused prep: W column-norm + transpose to f16 (atomic-free, per-block
//      column ownership), feats row-normalize -> f16, sumexp zeroing. ----
__global__ __launch_bounds__(256) void prep_kernel(const float* __restrict__ W,
                                                   const float* __restrict__ feats,
                                                   f16* __restrict__ wt,
                                                   f16* __restrict__ fn,
                                                   float* __restrict__ sumexp) {
    int bx = blockIdx.x, tid = threadIdx.x;
    if (bx < PREP_WBLK) {
        // ---- W-prep: this block owns 16 columns c0..c0+15 ----
        __shared__ float red[256];
        __shared__ float rqs[16];
        int c0 = bx * 16;
        int cl = tid & 15, dg = tid >> 4;
        int c = c0 + cl;
        float ss = 0.f;
        if (c < CC) {
            for (int d = dg; d < DD; d += 16) {
                float v = W[(size_t)d * CC + c];
                ss += v * v;
            }
        }
        red[tid] = ss;
        __syncthreads();
        if (tid < 16) {
            float s2 = 0.f;
            #pragma unroll
            for (int k = 0; k < 16; ++k) s2 += red[tid + 16 * k];
            rqs[tid] = rsqrtf(s2);
        }
        __syncthreads();
        // write wt[c][d] (f16), 16 consecutive-d lanes per c; W re-reads hit L1
        int c_loc = tid >> 4, dl = tid & 15;
        int cc = c0 + c_loc;
        float rq = rqs[c_loc];
        #pragma unroll 4
        for (int it = 0; it < 32; ++it) {
            int d = dl + it * 16;
            float v = (cc < CC) ? W[(size_t)d * CC + cc] * rq : 0.f;
            wt[(size_t)cc * DD + d] = (f16)v;
        }
    } else if (bx < PREP_WBLK + PREP_ZBLK) {
        int zb = bx - PREP_WBLK;
        float4 z = {0.f, 0.f, 0.f, 0.f};
        ((float4*)sumexp)[zb * 256 + tid] = z;   // 16*256*16B = 64KB
    } else {
        // ---- fnorm: one wave per feats row ----
        int fb = bx - PREP_WBLK - PREP_ZBLK;
        int wv = (fb * 256 + tid) >> 6;  // row id, 0..16383
        int lane = tid & 63;
        const float4* src = (const float4*)(feats + (size_t)wv * DD) + lane * 2;
        float4 a = src[0], b = src[1];
        float ss = a.x*a.x + a.y*a.y + a.z*a.z + a.w*a.w
                 + b.x*b.x + b.y*b.y + b.z*b.z + b.w*b.w;
        #pragma unroll
        for (int off = 32; off; off >>= 1) ss += __shfl_xor(ss, off);
        float r = rsqrtf(ss);
        f16x8 o;
        o[0]=(f16)(a.x*r); o[1]=(f16)(a.y*r); o[2]=(f16)(a.z*r); o[3]=(f16)(a.w*r);
        o[4]=(f16)(b.x*r); o[5]=(f16)(b.y*r); o[6]=(f16)(b.z*r); o[7]=(f16)(b.w*r);
        *(f16x8*)(fn + (size_t)wv * DD + lane * 8) = o;
    }
}

// ---- mega: blocks 0..31 = per-sample gather + ctc (self-contained, only
//      __syncthreads); blocks 32..1439 = gemm+sumexp. 18KB union LDS.
//      LDS channel-slot XOR swizzle: (row,ch) stored at slot ch^((row>>1)&3). ----
__global__ __launch_bounds__(256) void mega_kernel(const f16* __restrict__ A,
                                                   const f16* __restrict__ B,
                                                   const int* __restrict__ labels,
                                                   const int* __restrict__ in_lens,
                                                   const int* __restrict__ lab_lens,
                                                   float* __restrict__ sumexp,
                                                   float* __restrict__ lp_lab,
                                                   double* __restrict__ part) {
    __shared__ __align__(16) f16 sm[9216];   // 18KB: gemm 16KB | gath 16+2KB
    int bx = blockIdx.x;
    int tid = threadIdx.x;
    int w = tid >> 6, lane = tid & 63;
    int lm = lane & 15, hi = lane >> 4;
    int sw = (lm >> 1) & 3;                // fragment-read channel swizzle

    if (bx >= MEGA_GC) {
        // ================= GEMM section (identical math to R14) =============
        int j = bx - MEGA_GC;
        int bm = j & 127, bn = j >> 7;         // 1408 = 128 * 11
        int wm = w >> 1, wn = w & 1;           // 2x2 wave grid -> 64x64 per wave
        f32x4 acc[4][4];
        f32x4 zero = {0.f, 0.f, 0.f, 0.f};
        #pragma unroll
        for (int i = 0; i < 4; ++i)
            #pragma unroll
            for (int jj = 0; jj < 4; ++jj) acc[i][jj] = zero;

        for (int kb = 0; kb < 16; ++kb) {      // K=512, BK=32 (one MFMA K-step)
            #pragma unroll
            for (int p = 0; p < 2; ++p) {
                int s = p * 256 + tid;         // segment id, 16B each; 512 segs/tile
                int row = s >> 2;
                int ch = (s & 3) ^ ((row >> 1) & 3);   // swizzled source channel
                const f16* ga = A + (size_t)(bm * 128 + row) * DD + kb * 32 + ch * 8;
                const f16* gb = B + (size_t)(bn * 128 + row) * DD + kb * 32 + ch * 8;
                // LDS dest = wave-uniform base + lane*16 (contiguous, required)
                __builtin_amdgcn_global_load_lds((as1_void_ptr)ga,
                    (as3_void_ptr)&sm[(p * 256 + w * 64) * 8], 16, 0, 0);
                __builtin_amdgcn_global_load_lds((as1_void_ptr)gb,
                    (as3_void_ptr)&sm[4096 + (p * 256 + w * 64) * 8], 16, 0, 0);
            }
            __syncthreads();
            f16x8 af[4], bf[4];
            #pragma unroll
            for (int i = 0; i < 4; ++i)
                af[i] = *(const f16x8*)&sm[(wm * 64 + i * 16 + lm) * 32 + (hi ^ sw) * 8];
            #pragma unroll
            for (int jj = 0; jj < 4; ++jj)
                bf[jj] = *(const f16x8*)&sm[4096 + (wn * 64 + jj * 16 + lm) * 32 + (hi ^ sw) * 8];
            #pragma unroll
            for (int i = 0; i < 4; ++i)
                #pragma unroll
                for (int jj = 0; jj < 4; ++jj)
                    acc[i][jj] = __builtin_amdgcn_mfma_f32_16x16x32_f16(af[i], bf[jj], acc[i][jj], 0, 0, 0);
            __syncthreads();
        }
        // epilogue: per-row sum of exp(32*logit) over this block's 128 columns
        #pragma unroll
        for (int i = 0; i < 4; ++i) {
            float rs[4] = {0.f, 0.f, 0.f, 0.f};
            #pragma unroll
            for (int jj = 0; jj < 4; ++jj) {
                int c = bn * 128 + wn * 64 + jj * 16 + lm;   // C/D: col = lane&15
                bool ok = (c < CC);
                #pragma unroll
                for (int r = 0; r < 4; ++r)
                    rs[r] += ok ? fexp2(acc[i][jj][r] * (NORM_SCALE * LOG2E)) : 0.f;
            }
            #pragma unroll
            for (int off = 1; off < 16; off <<= 1) {        // sum over 16 cols
                #pragma unroll
                for (int r = 0; r < 4; ++r) rs[r] += __shfl_xor(rs[r], off);
            }
            if (lm == 0) {
                int rowb = bm * 128 + wm * 64 + i * 16 + hi * 4;  // row = quad*4+reg
                #pragma unroll
                for (int r = 0; r < 4; ++r) atomicAdd(&sumexp[rowb + r], rs[r]);
            }
        }
        return;
    }

    // ================= gather + ctc section (block n = bx) ==================
    int n = bx;
    int brow = tid >> 2;                       // B: row = label slot (tid<128)
    int bch = (tid & 3) ^ ((brow >> 1) & 3);
    int cls = (brow == 0 || brow > SS) ? 0 : labels[n * SS + brow - 1];
    const f16* gbB = B + (size_t)cls * DD + bch * 8;

    for (int thalf = 0; thalf < 2; ++thalf) {
        int t0a = thalf * 256;
        f32x4 acc[4][2];
        #pragma unroll
        for (int i = 0; i < 4; ++i) {
            acc[i][0] = (f32x4){0.f, 0.f, 0.f, 0.f};
            acc[i][1] = (f32x4){0.f, 0.f, 0.f, 0.f};
        }
        for (int kb = 0; kb < 16; ++kb) {
            #pragma unroll
            for (int it = 0; it < 4; ++it) {   // A-tile: 256 t-rows x 32 d
                int s = it * 256 + tid;
                int row = s >> 2;
                int ch = (s & 3) ^ ((row >> 1) & 3);
                const f16* ga = A + (size_t)((t0a + row) * NN + n) * DD + kb * 32 + ch * 8;
                __builtin_amdgcn_global_load_lds((as1_void_ptr)ga,
                    (as3_void_ptr)&sm[(it * 256 + w * 64) * 8], 16, 0, 0);
            }
            if (tid < 128)                     // B-tile: 32 rows x 32 d
                __builtin_amdgcn_global_load_lds((as1_void_ptr)(gbB + kb * 32),
                    (as3_void_ptr)&sm[8192 + (w * 64) * 8], 16, 0, 0);
            __syncthreads();
            f16x8 bf0 = *(const f16x8*)&sm[8192 + lm * 32 + (hi ^ sw) * 8];
            f16x8 bf1 = *(const f16x8*)&sm[8192 + (16 + lm) * 32 + (hi ^ sw) * 8];
            #pragma unroll
            for (int i = 0; i < 4; ++i) {      // wave w owns t-rows w*64..+64
                f16x8 af = *(const f16x8*)&sm[(w * 64 + i * 16 + lm) * 32 + (hi ^ sw) * 8];
                acc[i][0] = __builtin_amdgcn_mfma_f32_16x16x32_f16(af, bf0, acc[i][0], 0, 0, 0);
                acc[i][1] = __builtin_amdgcn_mfma_f32_16x16x32_f16(af, bf1, acc[i][1], 0, 0, 0);
            }
            __syncthreads();
        }
        // write raw scaled logits (no ls2: factored into final Msum)
        #pragma unroll
        for (int jn = 0; jn < 2; ++jn) {
            int jc = jn * 16 + lm;
            if (jc >= 31) continue;
            float* dst = lp_lab + ((size_t)n * 31 + jc) * TT + t0a;
            #pragma unroll
            for (int i = 0; i < 4; ++i)
                #pragma unroll
                for (int r = 0; r < 4; ++r)
                    dst[w * 64 + i * 16 + hi * 4 + r] = acc[i][jn][r] * (NORM_SCALE * LOG2E);
        }
    }
    __syncthreads();           // drain all waves' lp writes (vmcnt + barrier)
    if (w != 0) return;        // ctc runs on wave 0 only

    int s = lane;              // 64 lanes; states 0..60 valid
    bool valid = s < LL;
    int ext = (valid && (s & 1)) ? labels[n * SS + (s >> 1)] : 0;
    int jmap = (valid && (s & 1)) ? ((s >> 1) + 1) : 0;   // state -> class slot
    int ext2 = __shfl_up(ext, 2);
    double skipd = ((s >= 2) && valid && (ext != ext2)) ? 1.0 : 0.0;
    int Tin = in_lens[n];    // wave-uniform; freeze == stop at t = Tin-1
    const float4* g0 = (const float4*)(lp_lab + ((size_t)n * 31 + jmap) * TT);

    float4 cur = g0[0];
    float4 nxt = g0[1];
    float4 nx2 = g0[2];
    double beta = (s <= 1) ? (double)fexp2(cur.x) : 0.0;
    int Mi = 0;              // running log2 scale: alpha_raw = log2(beta) + Mi

    auto stepL = [&](float lp) {
        double P = (double)fexp2(lp);      // |lp| <= ~46.2: f32-safe
        double b1 = dpp_sr1_zero64(beta);
        double b2 = dpp_sr1_zero64(b1);
        beta = (beta + b1 + b2 * skipd) * P;
    };
    auto renorm = [&]() {
        int h = (int)(__double_as_longlong(beta) >> 32);  // beta>=0: monotone
        h = dpp_imax_level<0x111>(h);        // row_shr:1
        h = dpp_imax_level<0x112>(h);        // row_shr:2
        h = dpp_imax_level<0x114>(h);        // row_shr:4
        h = dpp_imax_level<0x118>(h);        // row_shr:8 -> row max 15/31/47/63
        int r0 = __builtin_amdgcn_readlane(h, 15);
        int r1 = __builtin_amdgcn_readlane(h, 31);
        int r2 = __builtin_amdgcn_readlane(h, 47);
        int r3 = __builtin_amdgcn_readlane(h, 63);
        int mx = max(max(r0, r1), max(r2, r3));
        int e11 = mx >> 20;                  // biased 11-bit exponent
        double scale = __longlong_as_double((long long)(2046 - e11) << 52);
        beta *= scale;
        Mi += e11 - 1023;
    };

    // group 0: t = 1..3 (Tin >= 481, always full)
    stepL(cur.y); stepL(cur.z); stepL(cur.w);
    renorm();
    int remaining = Tin - 4;   // steps left (total steps = Tin-1)
    int g = 1;
    while (remaining >= 4) {
        cur = nxt; nxt = nx2;
        int gi = g + 2; if (gi > 127) gi = 127;
        nx2 = g0[gi];
        stepL(cur.x); stepL(cur.y); stepL(cur.z); stepL(cur.w);
        renorm();
        remaining -= 4; ++g;
    }
    cur = nxt;                 // tail 0..3 steps
    if (remaining > 0) stepL(cur.x);
    if (remaining > 1) stepL(cur.y);
    if (remaining > 2) stepL(cur.z);

    int Ln = 2 * lab_lens[n] + 1;
    double last  = __shfl(beta, Ln - 1);
    double last2 = __shfl(beta, Ln - 2);
    double smv = last + last2;
    long long bb = __double_as_longlong(smv);
    int e = (int)(bb >> 52) - 1023;
    double mant = __longlong_as_double((bb & 0xFFFFFFFFFFFFFLL) | (1023LL << 52));
    if (s == 0)
        part[n] = (double)flog2((float)mant) + (double)(e + Mi);
}

// ---- final: Msum per n (f64, fixed order) + nll + deterministic sum ----
__global__ __launch_bounds__(1024) void final_kernel(const float* __restrict__ sumexp,
                                                     const int* __restrict__ in_lens,
                                                     const double* __restrict__ part,
                                                     float* __restrict__ out) {
    int tid = threadIdx.x;
    int v = tid >> 6, lane = tid & 63;     // 16 waves, 2 samples each
    __shared__ float nl[NN];
    #pragma unroll
    for (int k = 0; k < 2; ++k) {
        int n = v * 2 + k;
        int Tin = in_lens[n];
        double ms = 0.0;
        for (int t = lane; t < Tin; t += 64)
            ms += (double)flog2(sumexp[(size_t)t * NN + n]);
        #pragma unroll
        for (int off = 32; off; off >>= 1) ms += __shfl_xor(ms, off);
        if (lane == 0) nl[n] = (float)(-(part[n] - ms) * LN2);
    }
    __syncthreads();
    if (tid == 0) {
        float t = 0.f;
        for (int i = 0; i < NN; ++i) t += nl[i];
        out[0] = t;
    }
}

extern "C" void kernel_launch(void* const* d_in, const int* in_sizes, int n_in,
                              void* d_out, int out_size, void* d_ws, size_t ws_size,
                              hipStream_t stream) {
    const float* feats        = (const float*)d_in[0];
    const float* W            = (const float*)d_in[1];
    const int*   labeling     = (const int*)d_in[2];
    const int*   logit_lgts   = (const int*)d_in[3];
    const int*   labeling_lgts= (const int*)d_in[4];
    float* out = (float*)d_out;
    char* ws = (char*)d_ws;

    size_t off = 0;
    f16*   wt     = (f16*)(ws + off);   off += (size_t)CP * DD * 2;        // 1.44 MB
    f16*   fn     = (f16*)(ws + off);   off += (size_t)TT * NN * DD * 2;   // 16.8 MB
    float* sumexp = (float*)(ws + off); off += (size_t)TT * NN * 4;        // 64 KB
    float* lp_lab = (float*)(ws + off); off += (size_t)NN * 31 * TT * 4;   // 2.0 MB
    double* part  = (double*)(ws + off); off += NN * 8;

    prep_kernel<<<PREP_WBLK + PREP_ZBLK + PREP_FBLK, 256, 0, stream>>>(
        W, feats, wt, fn, sumexp);
    mega_kernel<<<MEGA_BLK, 256, 0, stream>>>(fn, wt, labeling, logit_lgts,
                                              labeling_lgts, sumexp, lp_lab, part);
    final_kernel<<<1, 1024, 0, stream>>>(sumexp, logit_lgts, part, out);

    (void)in_sizes; (void)n_in; (void)out_size; (void)ws_size;
}